// Round 13
// baseline (356.196 us; speedup 1.0000x reference)
//
#include <hip/hip_runtime.h>

#define NB 64
#define EDGES 1048576   /* 64*1024*16 */
#define NTOT  65536

struct __align__(8) CsrE { int s; float w; };

__global__ void k_zerof(float* __restrict__ p, int n){
  int i=blockIdx.x*256+threadIdx.x; if(i<n) p[i]=0.f;
}

// Y[ns x 128] = A[ns x 128] @ W[128 x 128]; W staged in LDS in two 64-row halves
// (32 KB); 128 rows/block, 8 rows x 8 cols per thread.
// G=true: A-row r gathered+pooled on the fly: relu(h[selold[r]]*score[selold[r]]),
//         with XCD-aware block swizzle (8 graphs pinned per XCD for L2 locality).
template<bool G>
__global__ __launch_bounds__(256) void matmul128(const float* __restrict__ X,
                                                 const float* __restrict__ W,
                                                 const int* __restrict__ selold,
                                                 const float* __restrict__ score,
                                                 float* __restrict__ Y, int gshift) {
  __shared__ float Wl[64*128];
  const int tr=threadIdx.x>>4, tc=threadIdx.x&15;
  int row0;
  if(G){
    int b=blockIdx.x, xcd=b&7, slot=b>>3, bpg=1<<gshift;
    int graph=xcd*8+(slot>>gshift), idx=slot&(bpg-1);
    row0 = graph*(bpg<<7) + (idx<<7) + tr*8;
  } else row0 = blockIdx.x*128 + tr*8;
  const int col0 = tc*8;
  int oldr[8]; float scr[8];
  #pragma unroll
  for(int r=0;r<8;++r){
    if(G){ oldr[r]=selold[row0+r]; scr[r]=score[oldr[r]]; }
    else { oldr[r]=row0+r; scr[r]=1.f; }
  }
  float acc[8][8];
  #pragma unroll
  for(int r=0;r<8;++r){
    #pragma unroll
    for(int c=0;c<8;++c) acc[r][c]=0.f;
  }
  for(int half=0; half<2; ++half){
    for (int t=threadIdx.x*4; t<64*128; t+=1024)
      *(float4*)&Wl[t] = *(const float4*)&W[half*8192+t];
    __syncthreads();
    const int kbase=half*64;
    for (int k=0;k<64;k+=4) {
      float4 a[8];
      #pragma unroll
      for(int r=0;r<8;++r){
        a[r]=*(const float4*)&X[(size_t)oldr[r]*128+kbase+k];
        if(G){
          a[r].x=fmaxf(a[r].x*scr[r],0.f); a[r].y=fmaxf(a[r].y*scr[r],0.f);
          a[r].z=fmaxf(a[r].z*scr[r],0.f); a[r].w=fmaxf(a[r].w*scr[r],0.f);
        }
      }
      #pragma unroll
      for(int kk=0;kk<4;++kk) {
        const float4 b0=*(const float4*)&Wl[(k+kk)*128+col0];
        const float4 b1=*(const float4*)&Wl[(k+kk)*128+col0+4];
        #pragma unroll
        for(int r=0;r<8;++r) {
          const float av = kk==0?a[r].x : kk==1?a[r].y : kk==2?a[r].z : a[r].w;
          acc[r][0]+=av*b0.x; acc[r][1]+=av*b0.y; acc[r][2]+=av*b0.z; acc[r][3]+=av*b0.w;
          acc[r][4]+=av*b1.x; acc[r][5]+=av*b1.y; acc[r][6]+=av*b1.z; acc[r][7]+=av*b1.w;
        }
      }
    }
    __syncthreads();
  }
  #pragma unroll
  for(int r=0;r<8;++r){
    float4 o0; o0.x=acc[r][0]; o0.y=acc[r][1]; o0.z=acc[r][2]; o0.w=acc[r][3];
    float4 o1; o1.x=acc[r][4]; o1.y=acc[r][5]; o1.z=acc[r][6]; o1.w=acc[r][7];
    *(float4*)&Y[(size_t)(row0+r)*128+col0]=o0;
    *(float4*)&Y[(size_t)(row0+r)*128+col0+4]=o1;
  }
}

// CSR build phase 1: 256 blocks (4 chunks x 64 graphs, XCD-pinned graph=(b&7)*8+(slot&7)).
// LDS histogram of 4096 edges -> per-chunk count/weight arrays (plain stores, no atomics).
__global__ __launch_bounds__(1024) void k_count(const int* __restrict__ edst,
        const float* __restrict__ ew, int* __restrict__ chunkcnt, float* __restrict__ chunkw){
  __shared__ int lc[1024];
  __shared__ float lw[1024];
  int b=blockIdx.x, i=threadIdx.x;
  int xcd=b&7, slot=b>>3;
  int graph=xcd*8+(slot&7), chunk=slot>>3;
  int e0=graph*16384+chunk*4096;
  lc[i]=0; lw[i]=0.f;
  __syncthreads();
  for(int e=e0+i; e<e0+4096; e+=1024){
    int dl=edst[e]&1023;
    atomicAdd(&lc[dl],1);
    atomicAdd(&lw[dl],ew[e]);
  }
  __syncthreads();
  chunkcnt[chunk*65536+graph*1024+i]=lc[i];
  chunkw  [chunk*65536+graph*1024+i]=lw[i];
}

// CSR build phase 2: per-graph scan of summed chunk histograms -> rowptr, dinv1, fill init.
__global__ __launch_bounds__(1024) void k_scan_graph(const int* __restrict__ chunkcnt,
        const float* __restrict__ chunkw, int* __restrict__ rowptr,
        float* __restrict__ dinv1, int* __restrict__ fill){
  __shared__ int pre[1024];
  int g=blockIdx.x, i=threadIdx.x;
  int o=g*1024+i;
  int c = chunkcnt[o]+chunkcnt[65536+o]+chunkcnt[131072+o]+chunkcnt[196608+o];
  float wsum = chunkw[o]+chunkw[65536+o]+chunkw[131072+o]+chunkw[196608+o];
  pre[i]=c; __syncthreads();
  for(int off=1;off<1024;off<<=1){
    int t=(i>=off)?pre[i-off]:0; __syncthreads();
    pre[i]+=t; __syncthreads();
  }
  int excl=pre[i]-c;
  int e0=g*16384;
  rowptr[o]=e0+excl;
  fill[o]=e0+excl;
  dinv1[o]=rsqrtf(wsum+1.0f);
  if(g==63 && i==1023) rowptr[65536]=EDGES;
}

// CSR build phase 3: scatter with global fill atomics. Same XCD pinning as k_count:
// graph g's counters (4 KB) and csr window (128 KB) only touched from XCD g/8 -> L2-local.
__global__ __launch_bounds__(1024) void k_scatter2(const int* __restrict__ esrc,
        const int* __restrict__ edst, const float* __restrict__ ew,
        int* __restrict__ fill, CsrE* __restrict__ csr){
  int b=blockIdx.x, i=threadIdx.x;
  int xcd=b&7, slot=b>>3;
  int graph=xcd*8+(slot&7), chunk=slot>>3;
  int e0=graph*16384+chunk*4096;
  int base=graph*1024;
  for(int e=e0+i; e<e0+4096; e+=1024){
    int dl=edst[e]&1023;
    int pos=atomicAdd(&fill[base+dl],1);
    CsrE ce; ce.s=esrc[e]; ce.w=ew[e];
    csr[pos]=ce;
  }
}

// fused stage-3 map composition: inv12 = inv2(inv1), map12 = sel1(sel2)
__global__ void k_compose(const int* __restrict__ inv1, const int* __restrict__ inv2,
                          const int* __restrict__ sel1, const int* __restrict__ sel2,
                          int* __restrict__ inv12, int* __restrict__ map12){
  int v=blockIdx.x*256+threadIdx.x;
  if(v<NTOT){ int t=inv1[v]; inv12[v]=(t>=0)?inv2[t]:-1; }
  if(v<16384){ map12[v]=sel1[sel2[v]]; }
}

// dinv[v] = rsqrt(1 + sum_{live e in row(d0)} w); 4-wide unrolled row walk.
__global__ void k_degrow(const int* __restrict__ rowptr, const CsrE* __restrict__ csr,
                         const int* __restrict__ map, const int* __restrict__ inv,
                         float* __restrict__ dinv, int ns){
  int v=blockIdx.x*256+threadIdx.x; if(v>=ns) return;
  int d0 = map[v];
  int rs=rowptr[d0], re=rowptr[d0+1];
  float s0=0.f,s1=0.f,s2=0.f,s3=0.f;
  int e=rs;
  for(; e+4<=re; e+=4){
    CsrE e0=csr[e], e1=csr[e+1], e2=csr[e+2], e3=csr[e+3];
    if(inv[e0.s]>=0) s0+=e0.w;
    if(inv[e1.s]>=0) s1+=e1.w;
    if(inv[e2.s]>=0) s2+=e2.w;
    if(inv[e3.s]>=0) s3+=e3.w;
  }
  for(; e<re; ++e){
    CsrE en=csr[e];
    if(inv[en.s]>=0) s0+=en.w;
  }
  dinv[v]=rsqrtf((s0+s1)+(s2+s3)+1.0f);
}

// 2 nodes per wave (half-wave of 32 lanes each, float4/lane = one 512B row per half).
// XCD-swizzled (8 graphs/XCD). Branch-free 4-edge groups via width-32 shfl broadcast;
// dead/pad edges carry coef 0 (row-0 load, L1-hot). Fused score (width-32 reduce).
template<bool F>
__global__ __launch_bounds__(256) void k_gather(const float* __restrict__ xw, const CsrE* __restrict__ csr,
        const int* __restrict__ rowptr, const int* __restrict__ map, const int* __restrict__ inv,
        const float* __restrict__ dinvv, const float* __restrict__ bias, const float* __restrict__ p,
        float* __restrict__ h, float* __restrict__ score, int gshift, int ns){
  int wv=threadIdx.x>>6, half=(threadIdx.x>>5)&1, hl=threadIdx.x&31;
  int b=blockIdx.x, xcd=b&7, slot=b>>3, bpg=1<<gshift;
  int graph=xcd*8+(slot>>gshift), idx=slot&(bpg-1);
  int v = graph*(bpg<<3) + (idx<<3) + wv*2 + half;   // 8 nodes per block
  if(v>=ns) return;
  int d0 = F? map[v] : v;
  float dv=dinvv[v];
  int rs=rowptr[d0], re=rowptr[d0+1];
  const int f4=hl*4;
  float4 accA={0.f,0.f,0.f,0.f}, accB={0.f,0.f,0.f,0.f};
  for(int base=rs; base<re; base+=32){
    int len=re-base; if(len>32) len=32;
    int sidx=0; float cf=0.f;
    if(hl<len){
      CsrE en=csr[base+hl];
      int s=en.s; bool live=true;
      if(F){ int t=inv[s]; live=(t>=0); s=live?t:0; }
      if(live){ sidx=s; cf=dinvv[s]*en.w; }
    }
    int len4=(len+3)&~3;
    for(int j=0;j<len4;j+=4){
      float c0=__shfl(cf,j,32),   c1=__shfl(cf,j+1,32);
      float c2=__shfl(cf,j+2,32), c3=__shfl(cf,j+3,32);
      int   s0=__shfl(sidx,j,32),   s1=__shfl(sidx,j+1,32);
      int   s2=__shfl(sidx,j+2,32), s3=__shfl(sidx,j+3,32);
      const float4 x0=*(const float4*)&xw[(size_t)s0*128+f4];
      const float4 x1=*(const float4*)&xw[(size_t)s1*128+f4];
      const float4 x2=*(const float4*)&xw[(size_t)s2*128+f4];
      const float4 x3=*(const float4*)&xw[(size_t)s3*128+f4];
      accA.x+=c0*x0.x; accA.y+=c0*x0.y; accA.z+=c0*x0.z; accA.w+=c0*x0.w;
      accB.x+=c1*x1.x; accB.y+=c1*x1.y; accB.z+=c1*x1.z; accB.w+=c1*x1.w;
      accA.x+=c2*x2.x; accA.y+=c2*x2.y; accA.z+=c2*x2.z; accA.w+=c2*x2.w;
      accB.x+=c3*x3.x; accB.y+=c3*x3.y; accB.z+=c3*x3.z; accB.w+=c3*x3.w;
    }
  }
  float4 acc; acc.x=accA.x+accB.x; acc.y=accA.y+accB.y;
  acc.z=accA.z+accB.z; acc.w=accA.w+accB.w;
  const float4 xv=*(const float4*)&xw[(size_t)v*128+f4];
  const float4 bv=*(const float4*)&bias[f4];
  float d2=dv*dv;
  float4 hv;
  hv.x=acc.x*dv + d2*xv.x + bv.x;
  hv.y=acc.y*dv + d2*xv.y + bv.y;
  hv.z=acc.z*dv + d2*xv.z + bv.z;
  hv.w=acc.w*dv + d2*xv.w + bv.w;
  *(float4*)&h[(size_t)v*128+f4]=hv;
  const float4 pv=*(const float4*)&p[f4];
  float z=hv.x*pv.x+hv.y*pv.y+hv.z*pv.z+hv.w*pv.w;
  float pp=pv.x*pv.x+pv.y*pv.y+pv.z*pv.z+pv.w*pv.w;
  #pragma unroll
  for(int m=16;m>0;m>>=1){ z+=__shfl_xor(z,m,32); pp+=__shfl_xor(pp,m,32); }
  if(hl==0) score[v]=1.0f/(1.0f+expf(-z/sqrtf(pp)));
}

// per-graph top-K via 4-pass MSB radix select on fp32 bit pattern (positive floats
// are order-isomorphic to their u32 bits). Exact jax.lax.top_k set semantics.
template<int N, int K>
__global__ __launch_bounds__(1024) void k_topk(const float* __restrict__ score,
                                               int* __restrict__ inv, int* __restrict__ selold){
  __shared__ unsigned hist[256];
  __shared__ unsigned sfx[256];
  __shared__ int c_sh, r_sh;
  __shared__ int pre[N];
  int g=blockIdx.x, i=threadIdx.x;
  int gv=g*N+i;
  unsigned key=__float_as_uint(score[gv]);
  int st=1;              // 0=rejected, 1=alive, 2=selected
  if(i==0) r_sh=K;
  __syncthreads();
  int R=K;
  #pragma unroll
  for(int pass=0; pass<4; ++pass){
    int shift=24-pass*8;
    if(i<256) hist[i]=0;
    __syncthreads();
    unsigned byte=(key>>shift)&255u;
    if(st==1) atomicAdd(&hist[byte],1u);
    __syncthreads();
    if(i<256) sfx[i]=hist[i];
    __syncthreads();
    for(int off=1; off<256; off<<=1){
      unsigned t=0;
      if(i<256 && i+off<256) t=sfx[i+off];
      __syncthreads();
      if(i<256) sfx[i]+=t;
      __syncthreads();
    }
    if(i<256){
      int A=(i<255)?(int)sfx[i+1]:0;
      if(A<R && R<=A+(int)hist[i]){ c_sh=i; r_sh=R-A; }
    }
    __syncthreads();
    int c=c_sh; R=r_sh;
    if(st==1){
      if((int)byte>c) st=2;
      else if((int)byte<c) st=0;
    }
    __syncthreads();
  }
  int alive=(st==1)?1:0;
  pre[i]=alive; __syncthreads();
  for(int off=1;off<N;off<<=1){
    int t=(i>=off)?pre[i-off]:0; __syncthreads();
    pre[i]+=t; __syncthreads();
  }
  int tie_rank=pre[i]-alive;
  int sel=(st==2)||(st==1 && tie_rank<R);
  __syncthreads();
  pre[i]=sel; __syncthreads();
  for(int off=1;off<N;off<<=1){
    int t=(i>=off)?pre[i-off]:0; __syncthreads();
    pre[i]+=t; __syncthreads();
  }
  int ng=g*K+pre[i]-1;
  if(sel && ng<NB*K){ inv[gv]=ng; selold[ng]=gv; }
  else inv[gv]=-1;
}

// per-graph readout with fused pool: v = relu(h3[selold3[.]] * score3[.])
__global__ __launch_bounds__(128) void k_readout(const float* __restrict__ h3, const float* __restrict__ score3,
                                                 const int* __restrict__ selold3,
                                                 const float* __restrict__ Wo, const float* __restrict__ bo,
                                                 float* __restrict__ out){
  __shared__ float red[128];
  int g=blockIdx.x, f=threadIdx.x;
  float mx=-3.4e38f, sm=0.f;
  for(int nd=0;nd<128;++nd){
    int old=selold3[g*128+nd];
    float v=fmaxf(h3[(size_t)old*128+f]*score3[old],0.f);
    mx=fmaxf(mx,v); sm+=v;
  }
  float mean=sm*(1.0f/128.0f);
  out[64+g*256+f]    =mx;
  out[64+g*256+128+f]=mean;
  red[f]=mx*Wo[f]+mean*Wo[128+f];
  __syncthreads();
  for(int off=64;off>0;off>>=1){ if(f<off) red[f]+=red[f+off]; __syncthreads(); }
  if(f==0){ float z=red[0]+bo[0]; out[g]=1.0f/(1.0f+expf(-z)); }
}

extern "C" void kernel_launch(void* const* d_in, const int* in_sizes, int n_in,
                              void* d_out, int out_size, void* d_ws, size_t ws_size,
                              hipStream_t stream) {
  (void)in_sizes; (void)n_in;
  const float* x  = (const float*)d_in[0];
  const int*   ei = (const int*)d_in[1];
  const float* ew = (const float*)d_in[2];
  // d_in[3] = batch_index (unused; graphs are equal-sized)
  const float* W1=(const float*)d_in[4];  const float* b1=(const float*)d_in[5];  const float* p1=(const float*)d_in[6];
  const float* W2=(const float*)d_in[7];  const float* b2=(const float*)d_in[8];  const float* p2=(const float*)d_in[9];
  const float* W3=(const float*)d_in[10]; const float* b3=(const float*)d_in[11]; const float* p3=(const float*)d_in[12];
  const float* Wo=(const float*)d_in[13]; const float* bo=(const float*)d_in[14];
  float* out=(float*)d_out;

  // ---- workspace layout (~77 MiB) ----
  char* ws=(char*)d_ws;
  size_t cur=0;
  float* slot0=(float*)(ws+cur); cur+=33554432;          // xw1 / xw2 / xw3
  float* slot1=(float*)(ws+cur); cur+=33554432;          // h1 / h2 / h3
  CsrE*  csr  =(CsrE*)(ws+cur);  cur+=(size_t)EDGES*8;   // 8 MB raw CSR
  int*   chunkcnt=(int*)(ws+cur); cur+=1048576;          // 4 x 65536 ints
  float* chunkw  =(float*)(ws+cur); cur+=1048576;        // 4 x 65536 floats
  int*   fill =(int*)  (ws+cur); cur+=262144;
  int*   rowptr=(int*) (ws+cur); cur+=262400;
  float* dinv1=(float*)(ws+cur); cur+=262144;
  float* dinv2=(float*)(ws+cur); cur+=131072;
  float* dinv3=(float*)(ws+cur); cur+=65536;
  float* sc1  =(float*)(ws+cur); cur+=262144;
  float* sc2  =(float*)(ws+cur); cur+=131072;
  float* sc3  =(float*)(ws+cur); cur+=65536;
  int*   inv1 =(int*)  (ws+cur); cur+=262144;
  int*   inv2 =(int*)  (ws+cur); cur+=131072;
  int*   invS =(int*)  (ws+cur); cur+=65536;
  int*   inv12=(int*)  (ws+cur); cur+=262144;
  int*   sel1 =(int*)  (ws+cur); cur+=131072;
  int*   sel2 =(int*)  (ws+cur); cur+=65536;
  int*   sel3 =(int*)  (ws+cur); cur+=32768;
  int*   map12=(int*)  (ws+cur); cur+=65536;

  if (ws_size < cur) {
    k_zerof<<<(out_size+255)/256,256,0,stream>>>(out,out_size);
    return;
  }

  const int* esrc=ei; const int* edst=ei+EDGES;

  // ---------------- stage 1: 65536 nodes, K=512/graph ----------------
  matmul128<false><<<NTOT/128,256,0,stream>>>(x,W1,nullptr,nullptr,slot0,0);
  k_count<<<256,1024,0,stream>>>(edst,ew,chunkcnt,chunkw);
  k_scan_graph<<<64,1024,0,stream>>>(chunkcnt,chunkw,rowptr,dinv1,fill);
  k_scatter2<<<256,1024,0,stream>>>(esrc,edst,ew,fill,csr);
  k_gather<false><<<NTOT/8,256,0,stream>>>(slot0,csr,rowptr,nullptr,nullptr,
                                           dinv1,b1,p1,slot1,sc1,7,NTOT);
  k_topk<1024,512><<<NB,1024,0,stream>>>(sc1,inv1,sel1);

  // ---------------- stage 2: 32768 nodes (space1), K=256 ----------------
  matmul128<true><<<32768/128,256,0,stream>>>(slot1,W2,sel1,sc1,slot0,2);
  k_degrow<<<32768/256,256,0,stream>>>(rowptr,csr,sel1,inv1,dinv2,32768);
  k_gather<true><<<32768/8,256,0,stream>>>(slot0,csr,rowptr,sel1,inv1,
                                           dinv2,b2,p2,slot1,sc2,6,32768);
  k_topk<512,256><<<NB,512,0,stream>>>(sc2,inv2,sel2);

  // ---------------- stage 3: 16384 nodes (space2), K=128 ----------------
  k_compose<<<NTOT/256,256,0,stream>>>(inv1,inv2,sel1,sel2,inv12,map12);
  matmul128<true><<<16384/128,256,0,stream>>>(slot1,W3,sel2,sc2,slot0,1);
  k_degrow<<<16384/256,256,0,stream>>>(rowptr,csr,map12,inv12,dinv3,16384);
  k_gather<true><<<16384/8,256,0,stream>>>(slot0,csr,rowptr,map12,inv12,
                                           dinv3,b3,p3,slot1,sc3,5,16384);
  k_topk<256,128><<<NB,256,0,stream>>>(sc3,invS,sel3);

  // ---------------- readout (fused pool) ----------------
  k_readout<<<NB,128,0,stream>>>(slot1,sc3,sel3,Wo,bo,out);
}

// Round 14
// 344.442 us; speedup vs baseline: 1.0341x; 1.0341x over previous
//
#include <hip/hip_runtime.h>

#define NB 64
#define EDGES 1048576   /* 64*1024*16 */
#define NTOT  65536

struct __align__(8) CsrE { int s; float w; };

__global__ void k_zerof(float* __restrict__ p, int n){
  int i=blockIdx.x*256+threadIdx.x; if(i<n) p[i]=0.f;
}

// Y[ns x 128] = A[ns x 128] @ W[128 x 128]; W staged in LDS in two 64-row halves
// (32 KB); 64 rows/block (grid = ns/64 -> 4 blocks/CU, fixes grid starvation),
// 4 rows x 8 cols per thread.
// G=true: A-row r gathered+pooled on the fly: relu(h[selold[r]]*score[selold[r]]),
//         with XCD-aware block swizzle (8 graphs pinned per XCD for L2 locality).
template<bool G>
__global__ __launch_bounds__(256) void matmul128(const float* __restrict__ X,
                                                 const float* __restrict__ W,
                                                 const int* __restrict__ selold,
                                                 const float* __restrict__ score,
                                                 float* __restrict__ Y, int gshift) {
  __shared__ float Wl[64*128];
  const int tr=threadIdx.x>>4, tc=threadIdx.x&15;
  int row0;
  if(G){
    int b=blockIdx.x, xcd=b&7, slot=b>>3, bpg=1<<gshift;
    int graph=xcd*8+(slot>>gshift), idx=slot&(bpg-1);
    row0 = graph*(bpg<<6) + (idx<<6) + tr*4;
  } else row0 = blockIdx.x*64 + tr*4;
  const int col0 = tc*8;
  int oldr[4]; float scr[4];
  #pragma unroll
  for(int r=0;r<4;++r){
    if(G){ oldr[r]=selold[row0+r]; scr[r]=score[oldr[r]]; }
    else { oldr[r]=row0+r; scr[r]=1.f; }
  }
  float acc[4][8];
  #pragma unroll
  for(int r=0;r<4;++r){
    #pragma unroll
    for(int c=0;c<8;++c) acc[r][c]=0.f;
  }
  for(int half=0; half<2; ++half){
    for (int t=threadIdx.x*4; t<64*128; t+=1024)
      *(float4*)&Wl[t] = *(const float4*)&W[half*8192+t];
    __syncthreads();
    const int kbase=half*64;
    for (int k=0;k<64;k+=4) {
      float4 a[4];
      #pragma unroll
      for(int r=0;r<4;++r){
        a[r]=*(const float4*)&X[(size_t)oldr[r]*128+kbase+k];
        if(G){
          a[r].x=fmaxf(a[r].x*scr[r],0.f); a[r].y=fmaxf(a[r].y*scr[r],0.f);
          a[r].z=fmaxf(a[r].z*scr[r],0.f); a[r].w=fmaxf(a[r].w*scr[r],0.f);
        }
      }
      #pragma unroll
      for(int kk=0;kk<4;++kk) {
        const float4 b0=*(const float4*)&Wl[(k+kk)*128+col0];
        const float4 b1=*(const float4*)&Wl[(k+kk)*128+col0+4];
        #pragma unroll
        for(int r=0;r<4;++r) {
          const float av = kk==0?a[r].x : kk==1?a[r].y : kk==2?a[r].z : a[r].w;
          acc[r][0]+=av*b0.x; acc[r][1]+=av*b0.y; acc[r][2]+=av*b0.z; acc[r][3]+=av*b0.w;
          acc[r][4]+=av*b1.x; acc[r][5]+=av*b1.y; acc[r][6]+=av*b1.z; acc[r][7]+=av*b1.w;
        }
      }
    }
    __syncthreads();
  }
  #pragma unroll
  for(int r=0;r<4;++r){
    float4 o0; o0.x=acc[r][0]; o0.y=acc[r][1]; o0.z=acc[r][2]; o0.w=acc[r][3];
    float4 o1; o1.x=acc[r][4]; o1.y=acc[r][5]; o1.z=acc[r][6]; o1.w=acc[r][7];
    *(float4*)&Y[(size_t)(row0+r)*128+col0]=o0;
    *(float4*)&Y[(size_t)(row0+r)*128+col0+4]=o1;
  }
}

// CSR build phase 1: 256 blocks (4 chunks x 64 graphs, XCD-pinned graph=(b&7)*8+(slot&7)).
// LDS histogram of 4096 edges -> per-chunk count/weight arrays (plain stores, no atomics).
__global__ __launch_bounds__(1024) void k_count(const int* __restrict__ edst,
        const float* __restrict__ ew, int* __restrict__ chunkcnt, float* __restrict__ chunkw){
  __shared__ int lc[1024];
  __shared__ float lw[1024];
  int b=blockIdx.x, i=threadIdx.x;
  int xcd=b&7, slot=b>>3;
  int graph=xcd*8+(slot&7), chunk=slot>>3;
  int e0=graph*16384+chunk*4096;
  lc[i]=0; lw[i]=0.f;
  __syncthreads();
  for(int e=e0+i; e<e0+4096; e+=1024){
    int dl=edst[e]&1023;
    atomicAdd(&lc[dl],1);
    atomicAdd(&lw[dl],ew[e]);
  }
  __syncthreads();
  chunkcnt[chunk*65536+graph*1024+i]=lc[i];
  chunkw  [chunk*65536+graph*1024+i]=lw[i];
}

// CSR build phase 2: per-graph scan of summed chunk histograms -> rowptr, dinv1, fill init.
__global__ __launch_bounds__(1024) void k_scan_graph(const int* __restrict__ chunkcnt,
        const float* __restrict__ chunkw, int* __restrict__ rowptr,
        float* __restrict__ dinv1, int* __restrict__ fill){
  __shared__ int pre[1024];
  int g=blockIdx.x, i=threadIdx.x;
  int o=g*1024+i;
  int c = chunkcnt[o]+chunkcnt[65536+o]+chunkcnt[131072+o]+chunkcnt[196608+o];
  float wsum = chunkw[o]+chunkw[65536+o]+chunkw[131072+o]+chunkw[196608+o];
  pre[i]=c; __syncthreads();
  for(int off=1;off<1024;off<<=1){
    int t=(i>=off)?pre[i-off]:0; __syncthreads();
    pre[i]+=t; __syncthreads();
  }
  int excl=pre[i]-c;
  int e0=g*16384;
  rowptr[o]=e0+excl;
  fill[o]=e0+excl;
  dinv1[o]=rsqrtf(wsum+1.0f);
  if(g==63 && i==1023) rowptr[65536]=EDGES;
}

// CSR build phase 3: scatter with global fill atomics. Same XCD pinning as k_count:
// graph g's counters (4 KB) and csr window (128 KB) only touched from XCD g/8 -> L2-local.
__global__ __launch_bounds__(1024) void k_scatter2(const int* __restrict__ esrc,
        const int* __restrict__ edst, const float* __restrict__ ew,
        int* __restrict__ fill, CsrE* __restrict__ csr){
  int b=blockIdx.x, i=threadIdx.x;
  int xcd=b&7, slot=b>>3;
  int graph=xcd*8+(slot&7), chunk=slot>>3;
  int e0=graph*16384+chunk*4096;
  int base=graph*1024;
  for(int e=e0+i; e<e0+4096; e+=1024){
    int dl=edst[e]&1023;
    int pos=atomicAdd(&fill[base+dl],1);
    CsrE ce; ce.s=esrc[e]; ce.w=ew[e];
    csr[pos]=ce;
  }
}

// dinv[v] = rsqrt(1 + sum_{live e in row(d0)} w); 4-wide unrolled row walk.
__global__ void k_degrow(const int* __restrict__ rowptr, const CsrE* __restrict__ csr,
                         const int* __restrict__ map, const int* __restrict__ inv,
                         float* __restrict__ dinv, int ns){
  int v=blockIdx.x*256+threadIdx.x; if(v>=ns) return;
  int d0 = map[v];
  int rs=rowptr[d0], re=rowptr[d0+1];
  float s0=0.f,s1=0.f,s2=0.f,s3=0.f;
  int e=rs;
  for(; e+4<=re; e+=4){
    CsrE e0=csr[e], e1=csr[e+1], e2=csr[e+2], e3=csr[e+3];
    if(inv[e0.s]>=0) s0+=e0.w;
    if(inv[e1.s]>=0) s1+=e1.w;
    if(inv[e2.s]>=0) s2+=e2.w;
    if(inv[e3.s]>=0) s3+=e3.w;
  }
  for(; e<re; ++e){
    CsrE en=csr[e];
    if(inv[en.s]>=0) s0+=en.w;
  }
  dinv[v]=rsqrtf((s0+s1)+(s2+s3)+1.0f);
}

// 2 nodes per wave (half-wave of 32 lanes each, float4/lane = one 512B row per half).
// XCD-swizzled (8 graphs/XCD). Branch-free 4-edge groups via width-32 shfl broadcast;
// dead/pad edges carry coef 0 (row-0 load, L1-hot). Fused score (width-32 reduce).
template<bool F>
__global__ __launch_bounds__(256) void k_gather(const float* __restrict__ xw, const CsrE* __restrict__ csr,
        const int* __restrict__ rowptr, const int* __restrict__ map, const int* __restrict__ inv,
        const float* __restrict__ dinvv, const float* __restrict__ bias, const float* __restrict__ p,
        float* __restrict__ h, float* __restrict__ score, int gshift, int ns){
  int wv=threadIdx.x>>6, half=(threadIdx.x>>5)&1, hl=threadIdx.x&31;
  int b=blockIdx.x, xcd=b&7, slot=b>>3, bpg=1<<gshift;
  int graph=xcd*8+(slot>>gshift), idx=slot&(bpg-1);
  int v = graph*(bpg<<3) + (idx<<3) + wv*2 + half;   // 8 nodes per block
  if(v>=ns) return;
  int d0 = F? map[v] : v;
  float dv=dinvv[v];
  int rs=rowptr[d0], re=rowptr[d0+1];
  const int f4=hl*4;
  float4 accA={0.f,0.f,0.f,0.f}, accB={0.f,0.f,0.f,0.f};
  for(int base=rs; base<re; base+=32){
    int len=re-base; if(len>32) len=32;
    int sidx=0; float cf=0.f;
    if(hl<len){
      CsrE en=csr[base+hl];
      int s=en.s; bool live=true;
      if(F){ int t=inv[s]; live=(t>=0); s=live?t:0; }
      if(live){ sidx=s; cf=dinvv[s]*en.w; }
    }
    int len4=(len+3)&~3;
    for(int j=0;j<len4;j+=4){
      float c0=__shfl(cf,j,32),   c1=__shfl(cf,j+1,32);
      float c2=__shfl(cf,j+2,32), c3=__shfl(cf,j+3,32);
      int   s0=__shfl(sidx,j,32),   s1=__shfl(sidx,j+1,32);
      int   s2=__shfl(sidx,j+2,32), s3=__shfl(sidx,j+3,32);
      const float4 x0=*(const float4*)&xw[(size_t)s0*128+f4];
      const float4 x1=*(const float4*)&xw[(size_t)s1*128+f4];
      const float4 x2=*(const float4*)&xw[(size_t)s2*128+f4];
      const float4 x3=*(const float4*)&xw[(size_t)s3*128+f4];
      accA.x+=c0*x0.x; accA.y+=c0*x0.y; accA.z+=c0*x0.z; accA.w+=c0*x0.w;
      accB.x+=c1*x1.x; accB.y+=c1*x1.y; accB.z+=c1*x1.z; accB.w+=c1*x1.w;
      accA.x+=c2*x2.x; accA.y+=c2*x2.y; accA.z+=c2*x2.z; accA.w+=c2*x2.w;
      accB.x+=c3*x3.x; accB.y+=c3*x3.y; accB.z+=c3*x3.z; accB.w+=c3*x3.w;
    }
  }
  float4 acc; acc.x=accA.x+accB.x; acc.y=accA.y+accB.y;
  acc.z=accA.z+accB.z; acc.w=accA.w+accB.w;
  const float4 xv=*(const float4*)&xw[(size_t)v*128+f4];
  const float4 bv=*(const float4*)&bias[f4];
  float d2=dv*dv;
  float4 hv;
  hv.x=acc.x*dv + d2*xv.x + bv.x;
  hv.y=acc.y*dv + d2*xv.y + bv.y;
  hv.z=acc.z*dv + d2*xv.z + bv.z;
  hv.w=acc.w*dv + d2*xv.w + bv.w;
  *(float4*)&h[(size_t)v*128+f4]=hv;
  const float4 pv=*(const float4*)&p[f4];
  float z=hv.x*pv.x+hv.y*pv.y+hv.z*pv.z+hv.w*pv.w;
  float pp=pv.x*pv.x+pv.y*pv.y+pv.z*pv.z+pv.w*pv.w;
  #pragma unroll
  for(int m=16;m>0;m>>=1){ z+=__shfl_xor(z,m,32); pp+=__shfl_xor(pp,m,32); }
  if(hl==0) score[v]=1.0f/(1.0f+expf(-z/sqrtf(pp)));
}

// per-graph top-K via 4-pass MSB radix select on fp32 bit pattern (positive floats
// are order-isomorphic to their u32 bits). Exact jax.lax.top_k set semantics.
// C=true (stage-2 instantiation): fused map composition epilogue — block g owns all
// inv2/sel2 entries its graph's compose range reads (visible after __syncthreads).
template<int N, int K, bool C>
__global__ __launch_bounds__(1024) void k_topk(const float* __restrict__ score,
                                               int* __restrict__ inv, int* __restrict__ selold,
                                               const int* __restrict__ inv1s, const int* __restrict__ sel1s,
                                               int* __restrict__ inv12, int* __restrict__ map12){
  __shared__ unsigned hist[256];
  __shared__ unsigned sfx[256];
  __shared__ int c_sh, r_sh;
  __shared__ int pre[N];
  int g=blockIdx.x, i=threadIdx.x;
  int gv=g*N+i;
  unsigned key=__float_as_uint(score[gv]);
  int st=1;              // 0=rejected, 1=alive, 2=selected
  if(i==0) r_sh=K;
  __syncthreads();
  int R=K;
  #pragma unroll
  for(int pass=0; pass<4; ++pass){
    int shift=24-pass*8;
    if(i<256) hist[i]=0;
    __syncthreads();
    unsigned byte=(key>>shift)&255u;
    if(st==1) atomicAdd(&hist[byte],1u);
    __syncthreads();
    if(i<256) sfx[i]=hist[i];
    __syncthreads();
    for(int off=1; off<256; off<<=1){
      unsigned t=0;
      if(i<256 && i+off<256) t=sfx[i+off];
      __syncthreads();
      if(i<256) sfx[i]+=t;
      __syncthreads();
    }
    if(i<256){
      int A=(i<255)?(int)sfx[i+1]:0;
      if(A<R && R<=A+(int)hist[i]){ c_sh=i; r_sh=R-A; }
    }
    __syncthreads();
    int c=c_sh; R=r_sh;
    if(st==1){
      if((int)byte>c) st=2;
      else if((int)byte<c) st=0;
    }
    __syncthreads();
  }
  int alive=(st==1)?1:0;
  pre[i]=alive; __syncthreads();
  for(int off=1;off<N;off<<=1){
    int t=(i>=off)?pre[i-off]:0; __syncthreads();
    pre[i]+=t; __syncthreads();
  }
  int tie_rank=pre[i]-alive;
  int sel=(st==2)||(st==1 && tie_rank<R);
  __syncthreads();
  pre[i]=sel; __syncthreads();
  for(int off=1;off<N;off<<=1){
    int t=(i>=off)?pre[i-off]:0; __syncthreads();
    pre[i]+=t; __syncthreads();
  }
  int ng=g*K+pre[i]-1;
  if(sel && ng<NB*K){ inv[gv]=ng; selold[ng]=gv; }
  else inv[gv]=-1;
  if(C){
    __syncthreads();   // make this block's inv/selold global writes visible in-block
    for(int t=i; t<1024; t+=N){
      int v0=g*1024+t;
      int q=inv1s[v0];
      inv12[v0]=(q>=0)?inv[q]:-1;
    }
    for(int t=i; t<256; t+=N){
      int v=g*256+t;
      map12[v]=sel1s[selold[v]];
    }
  }
}

// per-graph readout with fused pool: v = relu(h3[selold3[.]] * score3[.])
__global__ __launch_bounds__(128) void k_readout(const float* __restrict__ h3, const float* __restrict__ score3,
                                                 const int* __restrict__ selold3,
                                                 const float* __restrict__ Wo, const float* __restrict__ bo,
                                                 float* __restrict__ out){
  __shared__ float red[128];
  int g=blockIdx.x, f=threadIdx.x;
  float mx=-3.4e38f, sm=0.f;
  for(int nd=0;nd<128;++nd){
    int old=selold3[g*128+nd];
    float v=fmaxf(h3[(size_t)old*128+f]*score3[old],0.f);
    mx=fmaxf(mx,v); sm+=v;
  }
  float mean=sm*(1.0f/128.0f);
  out[64+g*256+f]    =mx;
  out[64+g*256+128+f]=mean;
  red[f]=mx*Wo[f]+mean*Wo[128+f];
  __syncthreads();
  for(int off=64;off>0;off>>=1){ if(f<off) red[f]+=red[f+off]; __syncthreads(); }
  if(f==0){ float z=red[0]+bo[0]; out[g]=1.0f/(1.0f+expf(-z)); }
}

extern "C" void kernel_launch(void* const* d_in, const int* in_sizes, int n_in,
                              void* d_out, int out_size, void* d_ws, size_t ws_size,
                              hipStream_t stream) {
  (void)in_sizes; (void)n_in;
  const float* x  = (const float*)d_in[0];
  const int*   ei = (const int*)d_in[1];
  const float* ew = (const float*)d_in[2];
  // d_in[3] = batch_index (unused; graphs are equal-sized)
  const float* W1=(const float*)d_in[4];  const float* b1=(const float*)d_in[5];  const float* p1=(const float*)d_in[6];
  const float* W2=(const float*)d_in[7];  const float* b2=(const float*)d_in[8];  const float* p2=(const float*)d_in[9];
  const float* W3=(const float*)d_in[10]; const float* b3=(const float*)d_in[11]; const float* p3=(const float*)d_in[12];
  const float* Wo=(const float*)d_in[13]; const float* bo=(const float*)d_in[14];
  float* out=(float*)d_out;

  // ---- workspace layout (~77 MiB) ----
  char* ws=(char*)d_ws;
  size_t cur=0;
  float* slot0=(float*)(ws+cur); cur+=33554432;          // xw1 / xw2 / xw3
  float* slot1=(float*)(ws+cur); cur+=33554432;          // h1 / h2 / h3
  CsrE*  csr  =(CsrE*)(ws+cur);  cur+=(size_t)EDGES*8;   // 8 MB raw CSR
  int*   chunkcnt=(int*)(ws+cur); cur+=1048576;          // 4 x 65536 ints
  float* chunkw  =(float*)(ws+cur); cur+=1048576;        // 4 x 65536 floats
  int*   fill =(int*)  (ws+cur); cur+=262144;
  int*   rowptr=(int*) (ws+cur); cur+=262400;
  float* dinv1=(float*)(ws+cur); cur+=262144;
  float* dinv2=(float*)(ws+cur); cur+=131072;
  float* dinv3=(float*)(ws+cur); cur+=65536;
  float* sc1  =(float*)(ws+cur); cur+=262144;
  float* sc2  =(float*)(ws+cur); cur+=131072;
  float* sc3  =(float*)(ws+cur); cur+=65536;
  int*   inv1 =(int*)  (ws+cur); cur+=262144;
  int*   inv2 =(int*)  (ws+cur); cur+=131072;
  int*   invS =(int*)  (ws+cur); cur+=65536;
  int*   inv12=(int*)  (ws+cur); cur+=262144;
  int*   sel1 =(int*)  (ws+cur); cur+=131072;
  int*   sel2 =(int*)  (ws+cur); cur+=65536;
  int*   sel3 =(int*)  (ws+cur); cur+=32768;
  int*   map12=(int*)  (ws+cur); cur+=65536;

  if (ws_size < cur) {
    k_zerof<<<(out_size+255)/256,256,0,stream>>>(out,out_size);
    return;
  }

  const int* esrc=ei; const int* edst=ei+EDGES;

  // ---------------- stage 1: 65536 nodes, K=512/graph ----------------
  matmul128<false><<<NTOT/64,256,0,stream>>>(x,W1,nullptr,nullptr,slot0,0);
  k_count<<<256,1024,0,stream>>>(edst,ew,chunkcnt,chunkw);
  k_scan_graph<<<64,1024,0,stream>>>(chunkcnt,chunkw,rowptr,dinv1,fill);
  k_scatter2<<<256,1024,0,stream>>>(esrc,edst,ew,fill,csr);
  k_gather<false><<<NTOT/8,256,0,stream>>>(slot0,csr,rowptr,nullptr,nullptr,
                                           dinv1,b1,p1,slot1,sc1,7,NTOT);
  k_topk<1024,512,false><<<NB,1024,0,stream>>>(sc1,inv1,sel1,nullptr,nullptr,nullptr,nullptr);

  // ---------------- stage 2: 32768 nodes (space1), K=256 ----------------
  matmul128<true><<<32768/64,256,0,stream>>>(slot1,W2,sel1,sc1,slot0,3);
  k_degrow<<<32768/256,256,0,stream>>>(rowptr,csr,sel1,inv1,dinv2,32768);
  k_gather<true><<<32768/8,256,0,stream>>>(slot0,csr,rowptr,sel1,inv1,
                                           dinv2,b2,p2,slot1,sc2,6,32768);
  k_topk<512,256,true><<<NB,512,0,stream>>>(sc2,inv2,sel2,inv1,sel1,inv12,map12);

  // ---------------- stage 3: 16384 nodes (space2), K=128 ----------------
  matmul128<true><<<16384/64,256,0,stream>>>(slot1,W3,sel2,sc2,slot0,2);
  k_degrow<<<16384/256,256,0,stream>>>(rowptr,csr,map12,inv12,dinv3,16384);
  k_gather<true><<<16384/8,256,0,stream>>>(slot0,csr,rowptr,map12,inv12,
                                           dinv3,b3,p3,slot1,sc3,5,16384);
  k_topk<256,128,false><<<NB,256,0,stream>>>(sc3,invS,sel3,nullptr,nullptr,nullptr,nullptr);

  // ---------------- readout (fused pool) ----------------
  k_readout<<<NB,128,0,stream>>>(slot1,sc3,sel3,Wo,bo,out);
}

// Round 15
// 342.056 us; speedup vs baseline: 1.0413x; 1.0070x over previous
//
#include <hip/hip_runtime.h>

#define NB 64
#define EDGES 1048576   /* 64*1024*16 */
#define NTOT  65536

struct __align__(8) CsrE { int s; float w; };

__global__ void k_zerof(float* __restrict__ p, int n){
  int i=blockIdx.x*256+threadIdx.x; if(i<n) p[i]=0.f;
}

// Y[ns x 128] = A[ns x 128] @ W[128 x 128]; W staged in LDS in two 64-row halves.
// Conflict-free skewed layout: float4 #c4 of row r lives at r*140 + 4*c4 + 4*(c4>>3)
// -> the 16 per-wave b128 reads are 2-way bank-aliased (free) instead of 4-way.
// 64 rows/block, 4 rows x 8 cols per thread.
// G=true: A-row r gathered+pooled on the fly: relu(h[selold[r]]*score[selold[r]]),
//         with XCD-aware block swizzle (8 graphs pinned per XCD for L2 locality).
template<bool G>
__global__ __launch_bounds__(256) void matmul128(const float* __restrict__ X,
                                                 const float* __restrict__ W,
                                                 const int* __restrict__ selold,
                                                 const float* __restrict__ score,
                                                 float* __restrict__ Y, int gshift) {
  __shared__ float Wl[64*140];
  const int tr=threadIdx.x>>4, tc=threadIdx.x&15;
  int row0;
  if(G){
    int b=blockIdx.x, xcd=b&7, slot=b>>3, bpg=1<<gshift;
    int graph=xcd*8+(slot>>gshift), idx=slot&(bpg-1);
    row0 = graph*(bpg<<6) + (idx<<6) + tr*4;
  } else row0 = blockIdx.x*64 + tr*4;
  const int col0 = tc*8;
  const int wbase0 = tc*8 + 4*(tc>>2);      // skewed base for this thread's two float4s
  int oldr[4]; float scr[4];
  #pragma unroll
  for(int r=0;r<4;++r){
    if(G){ oldr[r]=selold[row0+r]; scr[r]=score[oldr[r]]; }
    else { oldr[r]=row0+r; scr[r]=1.f; }
  }
  float acc[4][8];
  #pragma unroll
  for(int r=0;r<4;++r){
    #pragma unroll
    for(int c=0;c<8;++c) acc[r][c]=0.f;
  }
  for(int half=0; half<2; ++half){
    for (int t=threadIdx.x; t<64*32; t+=256){
      int row=t>>5, c4=t&31;
      *(float4*)&Wl[row*140 + 4*c4 + 4*(c4>>3)] = *(const float4*)&W[(half*64+row)*128 + c4*4];
    }
    __syncthreads();
    const int kbase=half*64;
    for (int k=0;k<64;k+=4) {
      float4 a[4];
      #pragma unroll
      for(int r=0;r<4;++r){
        a[r]=*(const float4*)&X[(size_t)oldr[r]*128+kbase+k];
        if(G){
          a[r].x=fmaxf(a[r].x*scr[r],0.f); a[r].y=fmaxf(a[r].y*scr[r],0.f);
          a[r].z=fmaxf(a[r].z*scr[r],0.f); a[r].w=fmaxf(a[r].w*scr[r],0.f);
        }
      }
      #pragma unroll
      for(int kk=0;kk<4;++kk) {
        const float* wrow=&Wl[(k+kk)*140 + wbase0];
        const float4 b0=*(const float4*)&wrow[0];
        const float4 b1=*(const float4*)&wrow[4];
        #pragma unroll
        for(int r=0;r<4;++r) {
          const float av = kk==0?a[r].x : kk==1?a[r].y : kk==2?a[r].z : a[r].w;
          acc[r][0]+=av*b0.x; acc[r][1]+=av*b0.y; acc[r][2]+=av*b0.z; acc[r][3]+=av*b0.w;
          acc[r][4]+=av*b1.x; acc[r][5]+=av*b1.y; acc[r][6]+=av*b1.z; acc[r][7]+=av*b1.w;
        }
      }
    }
    __syncthreads();
  }
  #pragma unroll
  for(int r=0;r<4;++r){
    float4 o0; o0.x=acc[r][0]; o0.y=acc[r][1]; o0.z=acc[r][2]; o0.w=acc[r][3];
    float4 o1; o1.x=acc[r][4]; o1.y=acc[r][5]; o1.z=acc[r][6]; o1.w=acc[r][7];
    *(float4*)&Y[(size_t)(row0+r)*128+col0]=o0;
    *(float4*)&Y[(size_t)(row0+r)*128+col0+4]=o1;
  }
}

// CSR build phase 1: 256 blocks (4 chunks x 64 graphs, XCD-pinned graph=(b&7)*8+(slot&7)).
// LDS histogram of 4096 edges -> per-chunk count/weight arrays (plain stores, no atomics).
__global__ __launch_bounds__(1024) void k_count(const int* __restrict__ edst,
        const float* __restrict__ ew, int* __restrict__ chunkcnt, float* __restrict__ chunkw){
  __shared__ int lc[1024];
  __shared__ float lw[1024];
  int b=blockIdx.x, i=threadIdx.x;
  int xcd=b&7, slot=b>>3;
  int graph=xcd*8+(slot&7), chunk=slot>>3;
  int e0=graph*16384+chunk*4096;
  lc[i]=0; lw[i]=0.f;
  __syncthreads();
  for(int e=e0+i; e<e0+4096; e+=1024){
    int dl=edst[e]&1023;
    atomicAdd(&lc[dl],1);
    atomicAdd(&lw[dl],ew[e]);
  }
  __syncthreads();
  chunkcnt[chunk*65536+graph*1024+i]=lc[i];
  chunkw  [chunk*65536+graph*1024+i]=lw[i];
}

// CSR build phase 2: per-graph scan of summed chunk histograms -> rowptr, dinv1, fill init.
__global__ __launch_bounds__(1024) void k_scan_graph(const int* __restrict__ chunkcnt,
        const float* __restrict__ chunkw, int* __restrict__ rowptr,
        float* __restrict__ dinv1, int* __restrict__ fill){
  __shared__ int pre[1024];
  int g=blockIdx.x, i=threadIdx.x;
  int o=g*1024+i;
  int c = chunkcnt[o]+chunkcnt[65536+o]+chunkcnt[131072+o]+chunkcnt[196608+o];
  float wsum = chunkw[o]+chunkw[65536+o]+chunkw[131072+o]+chunkw[196608+o];
  pre[i]=c; __syncthreads();
  for(int off=1;off<1024;off<<=1){
    int t=(i>=off)?pre[i-off]:0; __syncthreads();
    pre[i]+=t; __syncthreads();
  }
  int excl=pre[i]-c;
  int e0=g*16384;
  rowptr[o]=e0+excl;
  fill[o]=e0+excl;
  dinv1[o]=rsqrtf(wsum+1.0f);
  if(g==63 && i==1023) rowptr[65536]=EDGES;
}

// CSR build phase 3: scatter with global fill atomics. Same XCD pinning as k_count:
// graph g's counters (4 KB) and csr window (128 KB) only touched from XCD g/8 -> L2-local.
__global__ __launch_bounds__(1024) void k_scatter2(const int* __restrict__ esrc,
        const int* __restrict__ edst, const float* __restrict__ ew,
        int* __restrict__ fill, CsrE* __restrict__ csr){
  int b=blockIdx.x, i=threadIdx.x;
  int xcd=b&7, slot=b>>3;
  int graph=xcd*8+(slot&7), chunk=slot>>3;
  int e0=graph*16384+chunk*4096;
  int base=graph*1024;
  for(int e=e0+i; e<e0+4096; e+=1024){
    int dl=edst[e]&1023;
    int pos=atomicAdd(&fill[base+dl],1);
    CsrE ce; ce.s=esrc[e]; ce.w=ew[e];
    csr[pos]=ce;
  }
}

// 2 nodes per wave (half-wave of 32 lanes each, float4/lane = one 512B row per half).
// XCD-swizzled (8 graphs/XCD). Branch-free 4-edge groups via width-32 shfl broadcast;
// dead/pad edges carry coef 0 (row-0 load, L1-hot). Fused score (width-32 reduce).
template<bool F>
__global__ __launch_bounds__(256) void k_gather(const float* __restrict__ xw, const CsrE* __restrict__ csr,
        const int* __restrict__ rowptr, const int* __restrict__ map, const int* __restrict__ inv,
        const float* __restrict__ dinvv, const float* __restrict__ bias, const float* __restrict__ p,
        float* __restrict__ h, float* __restrict__ score, int gshift, int ns){
  int wv=threadIdx.x>>6, half=(threadIdx.x>>5)&1, hl=threadIdx.x&31;
  int b=blockIdx.x, xcd=b&7, slot=b>>3, bpg=1<<gshift;
  int graph=xcd*8+(slot>>gshift), idx=slot&(bpg-1);
  int v = graph*(bpg<<3) + (idx<<3) + wv*2 + half;   // 8 nodes per block
  if(v>=ns) return;
  int d0 = F? map[v] : v;
  float dv=dinvv[v];
  int rs=rowptr[d0], re=rowptr[d0+1];
  const int f4=hl*4;
  float4 accA={0.f,0.f,0.f,0.f}, accB={0.f,0.f,0.f,0.f};
  for(int base=rs; base<re; base+=32){
    int len=re-base; if(len>32) len=32;
    int sidx=0; float cf=0.f;
    if(hl<len){
      CsrE en=csr[base+hl];
      int s=en.s; bool live=true;
      if(F){ int t=inv[s]; live=(t>=0); s=live?t:0; }
      if(live){ sidx=s; cf=dinvv[s]*en.w; }
    }
    int len4=(len+3)&~3;
    for(int j=0;j<len4;j+=4){
      float c0=__shfl(cf,j,32),   c1=__shfl(cf,j+1,32);
      float c2=__shfl(cf,j+2,32), c3=__shfl(cf,j+3,32);
      int   s0=__shfl(sidx,j,32),   s1=__shfl(sidx,j+1,32);
      int   s2=__shfl(sidx,j+2,32), s3=__shfl(sidx,j+3,32);
      const float4 x0=*(const float4*)&xw[(size_t)s0*128+f4];
      const float4 x1=*(const float4*)&xw[(size_t)s1*128+f4];
      const float4 x2=*(const float4*)&xw[(size_t)s2*128+f4];
      const float4 x3=*(const float4*)&xw[(size_t)s3*128+f4];
      accA.x+=c0*x0.x; accA.y+=c0*x0.y; accA.z+=c0*x0.z; accA.w+=c0*x0.w;
      accB.x+=c1*x1.x; accB.y+=c1*x1.y; accB.z+=c1*x1.z; accB.w+=c1*x1.w;
      accA.x+=c2*x2.x; accA.y+=c2*x2.y; accA.z+=c2*x2.z; accA.w+=c2*x2.w;
      accB.x+=c3*x3.x; accB.y+=c3*x3.y; accB.z+=c3*x3.z; accB.w+=c3*x3.w;
    }
  }
  float4 acc; acc.x=accA.x+accB.x; acc.y=accA.y+accB.y;
  acc.z=accA.z+accB.z; acc.w=accA.w+accB.w;
  const float4 xv=*(const float4*)&xw[(size_t)v*128+f4];
  const float4 bv=*(const float4*)&bias[f4];
  float d2=dv*dv;
  float4 hv;
  hv.x=acc.x*dv + d2*xv.x + bv.x;
  hv.y=acc.y*dv + d2*xv.y + bv.y;
  hv.z=acc.z*dv + d2*xv.z + bv.z;
  hv.w=acc.w*dv + d2*xv.w + bv.w;
  *(float4*)&h[(size_t)v*128+f4]=hv;
  const float4 pv=*(const float4*)&p[f4];
  float z=hv.x*pv.x+hv.y*pv.y+hv.z*pv.z+hv.w*pv.w;
  float pp=pv.x*pv.x+pv.y*pv.y+pv.z*pv.z+pv.w*pv.w;
  #pragma unroll
  for(int m=16;m>0;m>>=1){ z+=__shfl_xor(z,m,32); pp+=__shfl_xor(pp,m,32); }
  if(hl==0) score[v]=1.0f/(1.0f+expf(-z/sqrtf(pp)));
}

// per-graph top-K via 4-pass MSB radix select on fp32 bit pattern. Exact jax.lax.top_k
// set semantics (ties -> smaller index).
// MODE 1 (topk1): fused degrow2 epilogue — dinv2 for the K new nodes (needs only this
//   block's inv/selold writes, visible after __syncthreads).
// MODE 2 (topk2): fused compose (inv12, map12) + degrow3 epilogue.
template<int N, int K, int MODE>
__global__ __launch_bounds__(1024) void k_topk(const float* __restrict__ score,
        int* __restrict__ inv, int* __restrict__ selold,
        const int* __restrict__ inv1s, const int* __restrict__ sel1s,
        int* __restrict__ inv12, int* __restrict__ map12,
        const int* __restrict__ rowptr, const CsrE* __restrict__ csr,
        float* __restrict__ dinv_out){
  __shared__ unsigned hist[256];
  __shared__ unsigned sfx[256];
  __shared__ int c_sh, r_sh;
  __shared__ int pre[N];
  int g=blockIdx.x, i=threadIdx.x;
  int gv=g*N+i;
  unsigned key=__float_as_uint(score[gv]);
  int st=1;              // 0=rejected, 1=alive, 2=selected
  if(i==0) r_sh=K;
  __syncthreads();
  int R=K;
  #pragma unroll
  for(int pass=0; pass<4; ++pass){
    int shift=24-pass*8;
    if(i<256) hist[i]=0;
    __syncthreads();
    unsigned byte=(key>>shift)&255u;
    if(st==1) atomicAdd(&hist[byte],1u);
    __syncthreads();
    if(i<256) sfx[i]=hist[i];
    __syncthreads();
    for(int off=1; off<256; off<<=1){
      unsigned t=0;
      if(i<256 && i+off<256) t=sfx[i+off];
      __syncthreads();
      if(i<256) sfx[i]+=t;
      __syncthreads();
    }
    if(i<256){
      int A=(i<255)?(int)sfx[i+1]:0;
      if(A<R && R<=A+(int)hist[i]){ c_sh=i; r_sh=R-A; }
    }
    __syncthreads();
    int c=c_sh; R=r_sh;
    if(st==1){
      if((int)byte>c) st=2;
      else if((int)byte<c) st=0;
    }
    __syncthreads();
  }
  int alive=(st==1)?1:0;
  pre[i]=alive; __syncthreads();
  for(int off=1;off<N;off<<=1){
    int t=(i>=off)?pre[i-off]:0; __syncthreads();
    pre[i]+=t; __syncthreads();
  }
  int tie_rank=pre[i]-alive;
  int sel=(st==2)||(st==1 && tie_rank<R);
  __syncthreads();
  pre[i]=sel; __syncthreads();
  for(int off=1;off<N;off<<=1){
    int t=(i>=off)?pre[i-off]:0; __syncthreads();
    pre[i]+=t; __syncthreads();
  }
  int ng=g*K+pre[i]-1;
  if(sel && ng<NB*K){ inv[gv]=ng; selold[ng]=gv; }
  else inv[gv]=-1;
  if(MODE==1){
    __syncthreads();   // this block's inv/selold global writes now visible in-block
    for(int t=i; t<K; t+=N){
      int v=g*K+t;
      int d0=selold[v];
      int rs=rowptr[d0], re=rowptr[d0+1];
      float s0=0.f,s1=0.f,s2=0.f,s3=0.f;
      int e=rs;
      for(; e+4<=re; e+=4){
        CsrE e0=csr[e], e1=csr[e+1], e2=csr[e+2], e3=csr[e+3];
        if(inv[e0.s]>=0) s0+=e0.w;
        if(inv[e1.s]>=0) s1+=e1.w;
        if(inv[e2.s]>=0) s2+=e2.w;
        if(inv[e3.s]>=0) s3+=e3.w;
      }
      for(; e<re; ++e){
        CsrE en=csr[e];
        if(inv[en.s]>=0) s0+=en.w;
      }
      dinv_out[v]=rsqrtf((s0+s1)+(s2+s3)+1.0f);
    }
  }
  if(MODE==2){
    __syncthreads();   // inv/selold visible
    for(int t=i; t<1024; t+=N){
      int v0=g*1024+t;
      int q=inv1s[v0];
      inv12[v0]=(q>=0)?inv[q]:-1;
    }
    for(int t=i; t<K; t+=N){
      int v=g*K+t;
      map12[v]=sel1s[selold[v]];
    }
    __syncthreads();   // inv12/map12 visible
    for(int t=i; t<K; t+=N){
      int v=g*K+t;
      int d0=map12[v];
      int rs=rowptr[d0], re=rowptr[d0+1];
      float s0=0.f,s1=0.f,s2=0.f,s3=0.f;
      int e=rs;
      for(; e+4<=re; e+=4){
        CsrE e0=csr[e], e1=csr[e+1], e2=csr[e+2], e3=csr[e+3];
        if(inv12[e0.s]>=0) s0+=e0.w;
        if(inv12[e1.s]>=0) s1+=e1.w;
        if(inv12[e2.s]>=0) s2+=e2.w;
        if(inv12[e3.s]>=0) s3+=e3.w;
      }
      for(; e<re; ++e){
        CsrE en=csr[e];
        if(inv12[en.s]>=0) s0+=en.w;
      }
      dinv_out[v]=rsqrtf((s0+s1)+(s2+s3)+1.0f);
    }
  }
}

// per-graph readout with fused pool: v = relu(h3[selold3[.]] * score3[.])
__global__ __launch_bounds__(128) void k_readout(const float* __restrict__ h3, const float* __restrict__ score3,
                                                 const int* __restrict__ selold3,
                                                 const float* __restrict__ Wo, const float* __restrict__ bo,
                                                 float* __restrict__ out){
  __shared__ float red[128];
  int g=blockIdx.x, f=threadIdx.x;
  float mx=-3.4e38f, sm=0.f;
  for(int nd=0;nd<128;++nd){
    int old=selold3[g*128+nd];
    float v=fmaxf(h3[(size_t)old*128+f]*score3[old],0.f);
    mx=fmaxf(mx,v); sm+=v;
  }
  float mean=sm*(1.0f/128.0f);
  out[64+g*256+f]    =mx;
  out[64+g*256+128+f]=mean;
  red[f]=mx*Wo[f]+mean*Wo[128+f];
  __syncthreads();
  for(int off=64;off>0;off>>=1){ if(f<off) red[f]+=red[f+off]; __syncthreads(); }
  if(f==0){ float z=red[0]+bo[0]; out[g]=1.0f/(1.0f+expf(-z)); }
}

extern "C" void kernel_launch(void* const* d_in, const int* in_sizes, int n_in,
                              void* d_out, int out_size, void* d_ws, size_t ws_size,
                              hipStream_t stream) {
  (void)in_sizes; (void)n_in;
  const float* x  = (const float*)d_in[0];
  const int*   ei = (const int*)d_in[1];
  const float* ew = (const float*)d_in[2];
  // d_in[3] = batch_index (unused; graphs are equal-sized)
  const float* W1=(const float*)d_in[4];  const float* b1=(const float*)d_in[5];  const float* p1=(const float*)d_in[6];
  const float* W2=(const float*)d_in[7];  const float* b2=(const float*)d_in[8];  const float* p2=(const float*)d_in[9];
  const float* W3=(const float*)d_in[10]; const float* b3=(const float*)d_in[11]; const float* p3=(const float*)d_in[12];
  const float* Wo=(const float*)d_in[13]; const float* bo=(const float*)d_in[14];
  float* out=(float*)d_out;

  // ---- workspace layout (~77 MiB) ----
  char* ws=(char*)d_ws;
  size_t cur=0;
  float* slot0=(float*)(ws+cur); cur+=33554432;          // xw1 / xw2 / xw3
  float* slot1=(float*)(ws+cur); cur+=33554432;          // h1 / h2 / h3
  CsrE*  csr  =(CsrE*)(ws+cur);  cur+=(size_t)EDGES*8;   // 8 MB raw CSR
  int*   chunkcnt=(int*)(ws+cur); cur+=1048576;          // 4 x 65536 ints
  float* chunkw  =(float*)(ws+cur); cur+=1048576;        // 4 x 65536 floats
  int*   fill =(int*)  (ws+cur); cur+=262144;
  int*   rowptr=(int*) (ws+cur); cur+=262400;
  float* dinv1=(float*)(ws+cur); cur+=262144;
  float* dinv2=(float*)(ws+cur); cur+=131072;
  float* dinv3=(float*)(ws+cur); cur+=65536;
  float* sc1  =(float*)(ws+cur); cur+=262144;
  float* sc2  =(float*)(ws+cur); cur+=131072;
  float* sc3  =(float*)(ws+cur); cur+=65536;
  int*   inv1 =(int*)  (ws+cur); cur+=262144;
  int*   inv2 =(int*)  (ws+cur); cur+=131072;
  int*   invS =(int*)  (ws+cur); cur+=65536;
  int*   inv12=(int*)  (ws+cur); cur+=262144;
  int*   sel1 =(int*)  (ws+cur); cur+=131072;
  int*   sel2 =(int*)  (ws+cur); cur+=65536;
  int*   sel3 =(int*)  (ws+cur); cur+=32768;
  int*   map12=(int*)  (ws+cur); cur+=65536;

  if (ws_size < cur) {
    k_zerof<<<(out_size+255)/256,256,0,stream>>>(out,out_size);
    return;
  }

  const int* esrc=ei; const int* edst=ei+EDGES;

  // ---------------- stage 1: 65536 nodes, K=512/graph ----------------
  matmul128<false><<<NTOT/64,256,0,stream>>>(x,W1,nullptr,nullptr,slot0,0);
  k_count<<<256,1024,0,stream>>>(edst,ew,chunkcnt,chunkw);
  k_scan_graph<<<64,1024,0,stream>>>(chunkcnt,chunkw,rowptr,dinv1,fill);
  k_scatter2<<<256,1024,0,stream>>>(esrc,edst,ew,fill,csr);
  k_gather<false><<<NTOT/8,256,0,stream>>>(slot0,csr,rowptr,nullptr,nullptr,
                                           dinv1,b1,p1,slot1,sc1,7,NTOT);
  k_topk<1024,512,1><<<NB,1024,0,stream>>>(sc1,inv1,sel1,nullptr,nullptr,nullptr,nullptr,
                                           rowptr,csr,dinv2);

  // ---------------- stage 2: 32768 nodes (space1), K=256 ----------------
  matmul128<true><<<32768/64,256,0,stream>>>(slot1,W2,sel1,sc1,slot0,3);
  k_gather<true><<<32768/8,256,0,stream>>>(slot0,csr,rowptr,sel1,inv1,
                                           dinv2,b2,p2,slot1,sc2,6,32768);
  k_topk<512,256,2><<<NB,512,0,stream>>>(sc2,inv2,sel2,inv1,sel1,inv12,map12,
                                         rowptr,csr,dinv3);

  // ---------------- stage 3: 16384 nodes (space2), K=128 ----------------
  matmul128<true><<<16384/64,256,0,stream>>>(slot1,W3,sel2,sc2,slot0,2);
  k_gather<true><<<16384/8,256,0,stream>>>(slot0,csr,rowptr,map12,inv12,
                                           dinv3,b3,p3,slot1,sc3,5,16384);
  k_topk<256,128,0><<<NB,256,0,stream>>>(sc3,invS,sel3,nullptr,nullptr,nullptr,nullptr,
                                         nullptr,nullptr,nullptr);

  // ---------------- readout (fused pool) ----------------
  k_readout<<<NB,128,0,stream>>>(slot1,sc3,sel3,Wo,bo,out);
}

// Round 16
// 339.864 us; speedup vs baseline: 1.0481x; 1.0064x over previous
//
#include <hip/hip_runtime.h>

#define NB 64
#define EDGES 1048576   /* 64*1024*16 */
#define NTOT  65536

struct __align__(8) CsrE { int s; float w; };

__global__ void k_zerof(float* __restrict__ p, int n){
  int i=blockIdx.x*256+threadIdx.x; if(i<n) p[i]=0.f;
}

// Y[ns x 128] = A[ns x 128] @ W[128 x 128]; W staged in LDS in two 64-row halves
// (skewed layout, 2-way aliasing). 64 rows/block, 4 rows x 8 cols per thread.
// X loads register-prefetched at distance 2 (a0/a1/a2 rotation) to hide L2/L3
// latency inside each W-half (syncthreads drains vmcnt at half boundaries).
// G=true: A-row r gathered+pooled on the fly: relu(h[selold[r]]*score[selold[r]]),
//         with XCD-aware block swizzle (8 graphs pinned per XCD for L2 locality).
template<bool G>
__global__ __launch_bounds__(256) void matmul128(const float* __restrict__ X,
                                                 const float* __restrict__ W,
                                                 const int* __restrict__ selold,
                                                 const float* __restrict__ score,
                                                 float* __restrict__ Y, int gshift) {
  __shared__ float Wl[64*140];
  const int tr=threadIdx.x>>4, tc=threadIdx.x&15;
  int row0;
  if(G){
    int b=blockIdx.x, xcd=b&7, slot=b>>3, bpg=1<<gshift;
    int graph=xcd*8+(slot>>gshift), idx=slot&(bpg-1);
    row0 = graph*(bpg<<6) + (idx<<6) + tr*4;
  } else row0 = blockIdx.x*64 + tr*4;
  const int col0 = tc*8;
  const int wbase0 = tc*8 + 4*(tc>>2);
  int oldr[4]; float scr[4];
  #pragma unroll
  for(int r=0;r<4;++r){
    if(G){ oldr[r]=selold[row0+r]; scr[r]=score[oldr[r]]; }
    else { oldr[r]=row0+r; scr[r]=1.f; }
  }
  float acc[4][8];
  #pragma unroll
  for(int r=0;r<4;++r){
    #pragma unroll
    for(int c=0;c<8;++c) acc[r][c]=0.f;
  }
  for(int half=0; half<2; ++half){
    for (int t=threadIdx.x; t<64*32; t+=256){
      int row=t>>5, c4=t&31;
      *(float4*)&Wl[row*140 + 4*c4 + 4*(c4>>3)] = *(const float4*)&W[(half*64+row)*128 + c4*4];
    }
    __syncthreads();
    const int kbase=half*64;
    float4 a0[4], a1[4];
    #pragma unroll
    for(int r=0;r<4;++r) a0[r]=*(const float4*)&X[(size_t)oldr[r]*128+kbase];
    #pragma unroll
    for(int r=0;r<4;++r) a1[r]=*(const float4*)&X[(size_t)oldr[r]*128+kbase+4];
    #pragma unroll
    for (int k=0;k<64;k+=4) {
      float4 a2[4];
      if(k+8<64){
        #pragma unroll
        for(int r=0;r<4;++r) a2[r]=*(const float4*)&X[(size_t)oldr[r]*128+kbase+k+8];
      }
      float4 a[4];
      #pragma unroll
      for(int r=0;r<4;++r){
        a[r]=a0[r];
        if(G){
          a[r].x=fmaxf(a[r].x*scr[r],0.f); a[r].y=fmaxf(a[r].y*scr[r],0.f);
          a[r].z=fmaxf(a[r].z*scr[r],0.f); a[r].w=fmaxf(a[r].w*scr[r],0.f);
        }
      }
      #pragma unroll
      for(int kk=0;kk<4;++kk) {
        const float* wrow=&Wl[(k+kk)*140 + wbase0];
        const float4 b0=*(const float4*)&wrow[0];
        const float4 b1=*(const float4*)&wrow[4];
        #pragma unroll
        for(int r=0;r<4;++r) {
          const float av = kk==0?a[r].x : kk==1?a[r].y : kk==2?a[r].z : a[r].w;
          acc[r][0]+=av*b0.x; acc[r][1]+=av*b0.y; acc[r][2]+=av*b0.z; acc[r][3]+=av*b0.w;
          acc[r][4]+=av*b1.x; acc[r][5]+=av*b1.y; acc[r][6]+=av*b1.z; acc[r][7]+=av*b1.w;
        }
      }
      #pragma unroll
      for(int r=0;r<4;++r){ a0[r]=a1[r]; a1[r]=a2[r]; }
    }
    __syncthreads();
  }
  #pragma unroll
  for(int r=0;r<4;++r){
    float4 o0; o0.x=acc[r][0]; o0.y=acc[r][1]; o0.z=acc[r][2]; o0.w=acc[r][3];
    float4 o1; o1.x=acc[r][4]; o1.y=acc[r][5]; o1.z=acc[r][6]; o1.w=acc[r][7];
    *(float4*)&Y[(size_t)(row0+r)*128+col0]=o0;
    *(float4*)&Y[(size_t)(row0+r)*128+col0+4]=o1;
  }
}

// CSR build phase 1: 256 blocks (4 chunks x 64 graphs, XCD-pinned graph=(b&7)*8+(slot&7)).
// LDS histogram of 4096 edges -> per-chunk count/weight arrays (plain stores, no atomics).
__global__ __launch_bounds__(1024) void k_count(const int* __restrict__ edst,
        const float* __restrict__ ew, int* __restrict__ chunkcnt, float* __restrict__ chunkw){
  __shared__ int lc[1024];
  __shared__ float lw[1024];
  int b=blockIdx.x, i=threadIdx.x;
  int xcd=b&7, slot=b>>3;
  int graph=xcd*8+(slot&7), chunk=slot>>3;
  int e0=graph*16384+chunk*4096;
  lc[i]=0; lw[i]=0.f;
  __syncthreads();
  for(int e=e0+i; e<e0+4096; e+=1024){
    int dl=edst[e]&1023;
    atomicAdd(&lc[dl],1);
    atomicAdd(&lw[dl],ew[e]);
  }
  __syncthreads();
  chunkcnt[chunk*65536+graph*1024+i]=lc[i];
  chunkw  [chunk*65536+graph*1024+i]=lw[i];
}

// CSR build phase 2: per-graph scan of summed chunk histograms -> rowptr, dinv1, fill init.
__global__ __launch_bounds__(1024) void k_scan_graph(const int* __restrict__ chunkcnt,
        const float* __restrict__ chunkw, int* __restrict__ rowptr,
        float* __restrict__ dinv1, int* __restrict__ fill){
  __shared__ int pre[1024];
  int g=blockIdx.x, i=threadIdx.x;
  int o=g*1024+i;
  int c = chunkcnt[o]+chunkcnt[65536+o]+chunkcnt[131072+o]+chunkcnt[196608+o];
  float wsum = chunkw[o]+chunkw[65536+o]+chunkw[131072+o]+chunkw[196608+o];
  pre[i]=c; __syncthreads();
  for(int off=1;off<1024;off<<=1){
    int t=(i>=off)?pre[i-off]:0; __syncthreads();
    pre[i]+=t; __syncthreads();
  }
  int excl=pre[i]-c;
  int e0=g*16384;
  rowptr[o]=e0+excl;
  fill[o]=e0+excl;
  dinv1[o]=rsqrtf(wsum+1.0f);
  if(g==63 && i==1023) rowptr[65536]=EDGES;
}

// CSR build phase 3: scatter with global fill atomics. Same XCD pinning as k_count:
// graph g's counters (4 KB) and csr window (128 KB) only touched from XCD g/8 -> L2-local.
__global__ __launch_bounds__(1024) void k_scatter2(const int* __restrict__ esrc,
        const int* __restrict__ edst, const float* __restrict__ ew,
        int* __restrict__ fill, CsrE* __restrict__ csr){
  int b=blockIdx.x, i=threadIdx.x;
  int xcd=b&7, slot=b>>3;
  int graph=xcd*8+(slot&7), chunk=slot>>3;
  int e0=graph*16384+chunk*4096;
  int base=graph*1024;
  for(int e=e0+i; e<e0+4096; e+=1024){
    int dl=edst[e]&1023;
    int pos=atomicAdd(&fill[base+dl],1);
    CsrE ce; ce.s=esrc[e]; ce.w=ew[e];
    csr[pos]=ce;
  }
}

// 2 nodes per wave (half-wave of 32 lanes each, float4/lane = one 512B row per half).
// XCD-swizzled (8 graphs/XCD). Branch-free 4-edge groups via width-32 shfl broadcast;
// dead/pad edges carry coef 0 (row-0 load, L1-hot). Fused score (width-32 reduce).
template<bool F>
__global__ __launch_bounds__(256) void k_gather(const float* __restrict__ xw, const CsrE* __restrict__ csr,
        const int* __restrict__ rowptr, const int* __restrict__ map, const int* __restrict__ inv,
        const float* __restrict__ dinvv, const float* __restrict__ bias, const float* __restrict__ p,
        float* __restrict__ h, float* __restrict__ score, int gshift, int ns){
  int wv=threadIdx.x>>6, half=(threadIdx.x>>5)&1, hl=threadIdx.x&31;
  int b=blockIdx.x, xcd=b&7, slot=b>>3, bpg=1<<gshift;
  int graph=xcd*8+(slot>>gshift), idx=slot&(bpg-1);
  int v = graph*(bpg<<3) + (idx<<3) + wv*2 + half;   // 8 nodes per block
  if(v>=ns) return;
  int d0 = F? map[v] : v;
  float dv=dinvv[v];
  int rs=rowptr[d0], re=rowptr[d0+1];
  const int f4=hl*4;
  float4 accA={0.f,0.f,0.f,0.f}, accB={0.f,0.f,0.f,0.f};
  for(int base=rs; base<re; base+=32){
    int len=re-base; if(len>32) len=32;
    int sidx=0; float cf=0.f;
    if(hl<len){
      CsrE en=csr[base+hl];
      int s=en.s; bool live=true;
      if(F){ int t=inv[s]; live=(t>=0); s=live?t:0; }
      if(live){ sidx=s; cf=dinvv[s]*en.w; }
    }
    int len4=(len+3)&~3;
    for(int j=0;j<len4;j+=4){
      float c0=__shfl(cf,j,32),   c1=__shfl(cf,j+1,32);
      float c2=__shfl(cf,j+2,32), c3=__shfl(cf,j+3,32);
      int   s0=__shfl(sidx,j,32),   s1=__shfl(sidx,j+1,32);
      int   s2=__shfl(sidx,j+2,32), s3=__shfl(sidx,j+3,32);
      const float4 x0=*(const float4*)&xw[(size_t)s0*128+f4];
      const float4 x1=*(const float4*)&xw[(size_t)s1*128+f4];
      const float4 x2=*(const float4*)&xw[(size_t)s2*128+f4];
      const float4 x3=*(const float4*)&xw[(size_t)s3*128+f4];
      accA.x+=c0*x0.x; accA.y+=c0*x0.y; accA.z+=c0*x0.z; accA.w+=c0*x0.w;
      accB.x+=c1*x1.x; accB.y+=c1*x1.y; accB.z+=c1*x1.z; accB.w+=c1*x1.w;
      accA.x+=c2*x2.x; accA.y+=c2*x2.y; accA.z+=c2*x2.z; accA.w+=c2*x2.w;
      accB.x+=c3*x3.x; accB.y+=c3*x3.y; accB.z+=c3*x3.z; accB.w+=c3*x3.w;
    }
  }
  float4 acc; acc.x=accA.x+accB.x; acc.y=accA.y+accB.y;
  acc.z=accA.z+accB.z; acc.w=accA.w+accB.w;
  const float4 xv=*(const float4*)&xw[(size_t)v*128+f4];
  const float4 bv=*(const float4*)&bias[f4];
  float d2=dv*dv;
  float4 hv;
  hv.x=acc.x*dv + d2*xv.x + bv.x;
  hv.y=acc.y*dv + d2*xv.y + bv.y;
  hv.z=acc.z*dv + d2*xv.z + bv.z;
  hv.w=acc.w*dv + d2*xv.w + bv.w;
  *(float4*)&h[(size_t)v*128+f4]=hv;
  const float4 pv=*(const float4*)&p[f4];
  float z=hv.x*pv.x+hv.y*pv.y+hv.z*pv.z+hv.w*pv.w;
  float pp=pv.x*pv.x+pv.y*pv.y+pv.z*pv.z+pv.w*pv.w;
  #pragma unroll
  for(int m=16;m>0;m>>=1){ z+=__shfl_xor(z,m,32); pp+=__shfl_xor(pp,m,32); }
  if(hl==0) score[v]=1.0f/(1.0f+expf(-z/sqrtf(pp)));
}

// per-graph top-K via 4-pass MSB radix select on fp32 bit pattern. Exact jax.lax.top_k
// set semantics (ties -> smaller index).
// MODE 1 (topk1): fused degrow2 epilogue — dinv2 for the K new nodes (needs only this
//   block's inv/selold writes, visible after __syncthreads).
// MODE 2 (topk2): fused compose (inv12, map12) + degrow3 epilogue.
template<int N, int K, int MODE>
__global__ __launch_bounds__(1024) void k_topk(const float* __restrict__ score,
        int* __restrict__ inv, int* __restrict__ selold,
        const int* __restrict__ inv1s, const int* __restrict__ sel1s,
        int* __restrict__ inv12, int* __restrict__ map12,
        const int* __restrict__ rowptr, const CsrE* __restrict__ csr,
        float* __restrict__ dinv_out){
  __shared__ unsigned hist[256];
  __shared__ unsigned sfx[256];
  __shared__ int c_sh, r_sh;
  __shared__ int pre[N];
  int g=blockIdx.x, i=threadIdx.x;
  int gv=g*N+i;
  unsigned key=__float_as_uint(score[gv]);
  int st=1;              // 0=rejected, 1=alive, 2=selected
  if(i==0) r_sh=K;
  __syncthreads();
  int R=K;
  #pragma unroll
  for(int pass=0; pass<4; ++pass){
    int shift=24-pass*8;
    if(i<256) hist[i]=0;
    __syncthreads();
    unsigned byte=(key>>shift)&255u;
    if(st==1) atomicAdd(&hist[byte],1u);
    __syncthreads();
    if(i<256) sfx[i]=hist[i];
    __syncthreads();
    for(int off=1; off<256; off<<=1){
      unsigned t=0;
      if(i<256 && i+off<256) t=sfx[i+off];
      __syncthreads();
      if(i<256) sfx[i]+=t;
      __syncthreads();
    }
    if(i<256){
      int A=(i<255)?(int)sfx[i+1]:0;
      if(A<R && R<=A+(int)hist[i]){ c_sh=i; r_sh=R-A; }
    }
    __syncthreads();
    int c=c_sh; R=r_sh;
    if(st==1){
      if((int)byte>c) st=2;
      else if((int)byte<c) st=0;
    }
    __syncthreads();
  }
  int alive=(st==1)?1:0;
  pre[i]=alive; __syncthreads();
  for(int off=1;off<N;off<<=1){
    int t=(i>=off)?pre[i-off]:0; __syncthreads();
    pre[i]+=t; __syncthreads();
  }
  int tie_rank=pre[i]-alive;
  int sel=(st==2)||(st==1 && tie_rank<R);
  __syncthreads();
  pre[i]=sel; __syncthreads();
  for(int off=1;off<N;off<<=1){
    int t=(i>=off)?pre[i-off]:0; __syncthreads();
    pre[i]+=t; __syncthreads();
  }
  int ng=g*K+pre[i]-1;
  if(sel && ng<NB*K){ inv[gv]=ng; selold[ng]=gv; }
  else inv[gv]=-1;
  if(MODE==1){
    __syncthreads();   // this block's inv/selold global writes now visible in-block
    for(int t=i; t<K; t+=N){
      int v=g*K+t;
      int d0=selold[v];
      int rs=rowptr[d0], re=rowptr[d0+1];
      float s0=0.f,s1=0.f,s2=0.f,s3=0.f;
      int e=rs;
      for(; e+4<=re; e+=4){
        CsrE e0=csr[e], e1=csr[e+1], e2=csr[e+2], e3=csr[e+3];
        if(inv[e0.s]>=0) s0+=e0.w;
        if(inv[e1.s]>=0) s1+=e1.w;
        if(inv[e2.s]>=0) s2+=e2.w;
        if(inv[e3.s]>=0) s3+=e3.w;
      }
      for(; e<re; ++e){
        CsrE en=csr[e];
        if(inv[en.s]>=0) s0+=en.w;
      }
      dinv_out[v]=rsqrtf((s0+s1)+(s2+s3)+1.0f);
    }
  }
  if(MODE==2){
    __syncthreads();   // inv/selold visible
    for(int t=i; t<1024; t+=N){
      int v0=g*1024+t;
      int q=inv1s[v0];
      inv12[v0]=(q>=0)?inv[q]:-1;
    }
    for(int t=i; t<K; t+=N){
      int v=g*K+t;
      map12[v]=sel1s[selold[v]];
    }
    __syncthreads();   // inv12/map12 visible
    for(int t=i; t<K; t+=N){
      int v=g*K+t;
      int d0=map12[v];
      int rs=rowptr[d0], re=rowptr[d0+1];
      float s0=0.f,s1=0.f,s2=0.f,s3=0.f;
      int e=rs;
      for(; e+4<=re; e+=4){
        CsrE e0=csr[e], e1=csr[e+1], e2=csr[e+2], e3=csr[e+3];
        if(inv12[e0.s]>=0) s0+=e0.w;
        if(inv12[e1.s]>=0) s1+=e1.w;
        if(inv12[e2.s]>=0) s2+=e2.w;
        if(inv12[e3.s]>=0) s3+=e3.w;
      }
      for(; e<re; ++e){
        CsrE en=csr[e];
        if(inv12[en.s]>=0) s0+=en.w;
      }
      dinv_out[v]=rsqrtf((s0+s1)+(s2+s3)+1.0f);
    }
  }
}

// per-graph readout with fused pool: v = relu(h3[selold3[.]] * score3[.])
__global__ __launch_bounds__(128) void k_readout(const float* __restrict__ h3, const float* __restrict__ score3,
                                                 const int* __restrict__ selold3,
                                                 const float* __restrict__ Wo, const float* __restrict__ bo,
                                                 float* __restrict__ out){
  __shared__ float red[128];
  int g=blockIdx.x, f=threadIdx.x;
  float mx=-3.4e38f, sm=0.f;
  for(int nd=0;nd<128;++nd){
    int old=selold3[g*128+nd];
    float v=fmaxf(h3[(size_t)old*128+f]*score3[old],0.f);
    mx=fmaxf(mx,v); sm+=v;
  }
  float mean=sm*(1.0f/128.0f);
  out[64+g*256+f]    =mx;
  out[64+g*256+128+f]=mean;
  red[f]=mx*Wo[f]+mean*Wo[128+f];
  __syncthreads();
  for(int off=64;off>0;off>>=1){ if(f<off) red[f]+=red[f+off]; __syncthreads(); }
  if(f==0){ float z=red[0]+bo[0]; out[g]=1.0f/(1.0f+expf(-z)); }
}

extern "C" void kernel_launch(void* const* d_in, const int* in_sizes, int n_in,
                              void* d_out, int out_size, void* d_ws, size_t ws_size,
                              hipStream_t stream) {
  (void)in_sizes; (void)n_in;
  const float* x  = (const float*)d_in[0];
  const int*   ei = (const int*)d_in[1];
  const float* ew = (const float*)d_in[2];
  // d_in[3] = batch_index (unused; graphs are equal-sized)
  const float* W1=(const float*)d_in[4];  const float* b1=(const float*)d_in[5];  const float* p1=(const float*)d_in[6];
  const float* W2=(const float*)d_in[7];  const float* b2=(const float*)d_in[8];  const float* p2=(const float*)d_in[9];
  const float* W3=(const float*)d_in[10]; const float* b3=(const float*)d_in[11]; const float* p3=(const float*)d_in[12];
  const float* Wo=(const float*)d_in[13]; const float* bo=(const float*)d_in[14];
  float* out=(float*)d_out;

  // ---- workspace layout (~77 MiB) ----
  char* ws=(char*)d_ws;
  size_t cur=0;
  float* slot0=(float*)(ws+cur); cur+=33554432;          // xw1 / xw2 / xw3
  float* slot1=(float*)(ws+cur); cur+=33554432;          // h1 / h2 / h3
  CsrE*  csr  =(CsrE*)(ws+cur);  cur+=(size_t)EDGES*8;   // 8 MB raw CSR
  int*   chunkcnt=(int*)(ws+cur); cur+=1048576;          // 4 x 65536 ints
  float* chunkw  =(float*)(ws+cur); cur+=1048576;        // 4 x 65536 floats
  int*   fill =(int*)  (ws+cur); cur+=262144;
  int*   rowptr=(int*) (ws+cur); cur+=262400;
  float* dinv1=(float*)(ws+cur); cur+=262144;
  float* dinv2=(float*)(ws+cur); cur+=131072;
  float* dinv3=(float*)(ws+cur); cur+=65536;
  float* sc1  =(float*)(ws+cur); cur+=262144;
  float* sc2  =(float*)(ws+cur); cur+=131072;
  float* sc3  =(float*)(ws+cur); cur+=65536;
  int*   inv1 =(int*)  (ws+cur); cur+=262144;
  int*   inv2 =(int*)  (ws+cur); cur+=131072;
  int*   invS =(int*)  (ws+cur); cur+=65536;
  int*   inv12=(int*)  (ws+cur); cur+=262144;
  int*   sel1 =(int*)  (ws+cur); cur+=131072;
  int*   sel2 =(int*)  (ws+cur); cur+=65536;
  int*   sel3 =(int*)  (ws+cur); cur+=32768;
  int*   map12=(int*)  (ws+cur); cur+=65536;

  if (ws_size < cur) {
    k_zerof<<<(out_size+255)/256,256,0,stream>>>(out,out_size);
    return;
  }

  const int* esrc=ei; const int* edst=ei+EDGES;

  // ---------------- stage 1: 65536 nodes, K=512/graph ----------------
  matmul128<false><<<NTOT/64,256,0,stream>>>(x,W1,nullptr,nullptr,slot0,0);
  k_count<<<256,1024,0,stream>>>(edst,ew,chunkcnt,chunkw);
  k_scan_graph<<<64,1024,0,stream>>>(chunkcnt,chunkw,rowptr,dinv1,fill);
  k_scatter2<<<256,1024,0,stream>>>(esrc,edst,ew,fill,csr);
  k_gather<false><<<NTOT/8,256,0,stream>>>(slot0,csr,rowptr,nullptr,nullptr,
                                           dinv1,b1,p1,slot1,sc1,7,NTOT);
  k_topk<1024,512,1><<<NB,1024,0,stream>>>(sc1,inv1,sel1,nullptr,nullptr,nullptr,nullptr,
                                           rowptr,csr,dinv2);

  // ---------------- stage 2: 32768 nodes (space1), K=256 ----------------
  matmul128<true><<<32768/64,256,0,stream>>>(slot1,W2,sel1,sc1,slot0,3);
  k_gather<true><<<32768/8,256,0,stream>>>(slot0,csr,rowptr,sel1,inv1,
                                           dinv2,b2,p2,slot1,sc2,6,32768);
  k_topk<512,256,2><<<NB,512,0,stream>>>(sc2,inv2,sel2,inv1,sel1,inv12,map12,
                                         rowptr,csr,dinv3);

  // ---------------- stage 3: 16384 nodes (space2), K=128 ----------------
  matmul128<true><<<16384/64,256,0,stream>>>(slot1,W3,sel2,sc2,slot0,2);
  k_gather<true><<<16384/8,256,0,stream>>>(slot0,csr,rowptr,map12,inv12,
                                           dinv3,b3,p3,slot1,sc3,5,16384);
  k_topk<256,128,0><<<NB,256,0,stream>>>(sc3,invS,sel3,nullptr,nullptr,nullptr,nullptr,
                                         nullptr,nullptr,nullptr);

  // ---------------- readout (fused pool) ----------------
  k_readout<<<NB,128,0,stream>>>(slot1,sc3,sel3,Wo,bo,out);
}